// Round 1
// 153.265 us; speedup vs baseline: 1.1206x; 1.1206x over previous
//
#include <hip/hip_runtime.h>

// ---- problem constants (fixed by reference setup_inputs) ----
constexpr int B_  = 32;
constexpr int Na  = 512;
constexpr int Nv  = 256;
constexpr int D   = 384;

constexpr int BK  = 32;        // k-chunk per iteration
constexpr int NK  = D / BK;    // 12 k-iters

// fp8 operand regions: one 32-row group x 384 k = 12 chunks x 1 KB = 12 KB.
// Unit (group, kc) internal layout: byte = h2*512 + r*16 + j, holding
// value[row r][k = kc*32 + h2*16 + j]  (r = lane&31, k-half h2 = lane>>5).
// The (lane,byte)->k permutation is IDENTICAL for the MFMA A-slot and B-slot,
// so the contraction is exact for either operand role -> operands are swappable.
constexpr int AGROUPS = B_ * 16;   // 512 groups (bi*16+rg), rows linear
constexpr int BGROUPS = B_ * 8;    // 256 groups (bj*8+cg), rows linear
constexpr size_t GROUP_BYTES = 12 * 1024;

typedef long  long2v   __attribute__((ext_vector_type(2)));
typedef int   int4v    __attribute__((ext_vector_type(4)));
typedef float floatx16 __attribute__((ext_vector_type(16)));

// ---- K1: zero output + fp32 -> fp8(e4m3 OCP) conversion, BOTH sides coalesced ----
// (unchanged from previous round — it was not the measured bottleneck)
__global__ void convert_fp8_kernel(const float* __restrict__ a, const float* __restrict__ v,
                                   unsigned char* __restrict__ a8,
                                   unsigned char* __restrict__ b8,
                                   float* __restrict__ out) {
    int gid = blockIdx.x * blockDim.x + threadIdx.x;
    if (gid < B_ * B_) out[gid] = 0.0f;    // d_out is poisoned before every launch

    const float* src;
    unsigned char* dst;
    int blk = blockIdx.x;
    if (blk < AGROUPS) {                       // A rows are linear: group*32 + r
        src = a + (size_t)blk * 32 * D;
        dst = a8 + (size_t)blk * GROUP_BYTES;
    } else {
        int b2 = blk - AGROUPS;
        src = v + (size_t)b2 * 32 * D;
        dst = b8 + (size_t)b2 * GROUP_BYTES;
    }
    const int t = threadIdx.x;
    const int r = t >> 3, q = t & 7;

    #pragma unroll
    for (int p = 0; p < 3; ++p) {
        int k0 = p * 128 + q * 16;
        const float4* s4 = (const float4*)(src + (size_t)r * D + k0);
        float4 f0 = s4[0], f1 = s4[1], f2 = s4[2], f3 = s4[3];
        int w0 = 0, w1 = 0, w2 = 0, w3 = 0;
        w0 = __builtin_amdgcn_cvt_pk_fp8_f32(f0.x, f0.y, w0, false);
        w0 = __builtin_amdgcn_cvt_pk_fp8_f32(f0.z, f0.w, w0, true);
        w1 = __builtin_amdgcn_cvt_pk_fp8_f32(f1.x, f1.y, w1, false);
        w1 = __builtin_amdgcn_cvt_pk_fp8_f32(f1.z, f1.w, w1, true);
        w2 = __builtin_amdgcn_cvt_pk_fp8_f32(f2.x, f2.y, w2, false);
        w2 = __builtin_amdgcn_cvt_pk_fp8_f32(f2.z, f2.w, w2, true);
        w3 = __builtin_amdgcn_cvt_pk_fp8_f32(f3.x, f3.y, w3, false);
        w3 = __builtin_amdgcn_cvt_pk_fp8_f32(f3.z, f3.w, w3, true);
        int kc = k0 >> 5;
        int h2 = (k0 >> 4) & 1;
        int4v o = { w0, w1, w2, w3 };
        *(int4v*)(dst + (size_t)kc * 1024 + h2 * 512 + r * 16) = o;
    }
}

// sum of exp2(a[i] * 1/(tau*ln2)) over one accumulator, pairwise tree
__device__ __forceinline__ float expsum16(floatx16 a) {
    constexpr float INV_TAU_LN2 = 0.7213475204444817f;  // 1/(tau*ln2), tau=2
    float e[16];
    #pragma unroll
    for (int i = 0; i < 16; ++i) e[i] = exp2f(a[i] * INV_TAU_LN2);
    float t0 = (e[0] + e[1])  + (e[2] + e[3]);
    float t1 = (e[4] + e[5])  + (e[6] + e[7]);
    float t2 = (e[8] + e[9])  + (e[10] + e[11]);
    float t3 = (e[12] + e[13]) + (e[14] + e[15]);
    return (t0 + t1) + (t2 + t3);
}

// ---- K2: fused fp8 GEMM + logsumexp-pool, wave-independent, NO LDS, NO mainloop barriers ----
// Operand fragments are lane-linear 16B, so B loads straight into VGPRs
// (global_load_dwordx4) — LDS staging existed only for cross-wave sharing,
// which L1/L2 now provide (full fp8 set = 9.4 MB, L2-resident).
// OPERAND SWAP: feed V as the MFMA A-slot, audio as the B-slot ->
// D col (lane&31) = audio row, D rows (regs) = v indices -> the Nv exp-sum is
// a per-thread register reduction + ONE shfl_xor(32). No shuffle trees, no ms[][].
// Wave tile: 64 audio rows (2 groups) x 128 v (4 units) -> acc[2][4] = 128 AGPRs,
// 16 MFMA / k-iter; 2 phases cover all 256 v. Register double-buffered operand
// prefetch: compiler emits counted vmcnt (no vmcnt(0) drain anywhere in the loop).
__global__ __launch_bounds__(256, 2) void gemm_lse_kernel(
        const unsigned char* __restrict__ a8,
        const unsigned char* __restrict__ b8,
        float* __restrict__ out)
{
    const int tid  = threadIdx.x;
    const int lane = tid & 63;
    const int wv   = tid >> 6;

    // XCD-chunked decode (block -> XCD = blockIdx%8 heuristic): bi tied to XCD
    // => per-XCD L2 working set = A(4 bi)=786KB + B(all)=3.1MB ~= 3.9MB <= 4MB.
    // Block's 4 waves share (bi,bj), differ in rp => identical B reads (L1 hit).
    int b = blockIdx.x;
    const int xcd   = b & 7;      b >>= 3;
    const int bi_lo = b & 3;      b >>= 2;
    const int pr    = b & 1;      b >>= 1;
    const int bj    = b;                      // 0..31
    const int bi    = xcd * 4 + bi_lo;        // 0..31
    const int rp    = pr * 4 + wv;            // 0..7 -> rows 64*rp .. +63

    const size_t laneoff = (size_t)lane * 16;
    const unsigned char* pa0 = a8 + (size_t)(bi * 16 + rp * 2) * GROUP_BYTES + laneoff;
    const unsigned char* pa1 = pa0 + GROUP_BYTES;

    float s0 = 0.0f, s1 = 0.0f;   // per-thread exp2-sums for audio rows
                                  // (rp*2)*32+(lane&31) and (rp*2+1)*32+(lane&31)

    #pragma unroll
    for (int ph = 0; ph < 2; ++ph) {
        const unsigned char* pb = b8 + (size_t)(bj * 8 + ph * 4) * GROUP_BYTES + laneoff;

        floatx16 acc[2][4];
        #pragma unroll
        for (int r = 0; r < 2; ++r)
            #pragma unroll
            for (int c = 0; c < 4; ++c)
                acc[r][c] = (floatx16)(0.0f);

        long2v A0 = *(const long2v*)pa0;
        long2v A1 = *(const long2v*)pa1;
        long2v V[4];
        #pragma unroll
        for (int c = 0; c < 4; ++c)
            V[c] = *(const long2v*)(pb + (size_t)c * GROUP_BYTES);

        #pragma unroll
        for (int k = 0; k < NK; ++k) {
            // issue next-iter operand loads first (reg double-buffer; one full
            // 16-MFMA phase ~512 pipe-cy of slack covers L2-hit latency)
            long2v nA0, nA1, nV[4];
            if (k + 1 < NK) {
                const size_t o = (size_t)(k + 1) * 1024;
                nA0 = *(const long2v*)(pa0 + o);
                nA1 = *(const long2v*)(pa1 + o);
                #pragma unroll
                for (int c = 0; c < 4; ++c)
                    nV[c] = *(const long2v*)(pb + (size_t)c * GROUP_BYTES + o);
            }
            // 16 MFMAs = 8 independent 2-chains (swapped operands: V in A-slot)
            __builtin_amdgcn_s_setprio(1);
            #pragma unroll
            for (int c = 0; c < 4; ++c) {
                acc[0][c] = __builtin_amdgcn_mfma_f32_32x32x16_fp8_fp8(V[c].x, A0.x, acc[0][c], 0, 0, 0);
                acc[1][c] = __builtin_amdgcn_mfma_f32_32x32x16_fp8_fp8(V[c].x, A1.x, acc[1][c], 0, 0, 0);
            }
            #pragma unroll
            for (int c = 0; c < 4; ++c) {
                acc[0][c] = __builtin_amdgcn_mfma_f32_32x32x16_fp8_fp8(V[c].y, A0.y, acc[0][c], 0, 0, 0);
                acc[1][c] = __builtin_amdgcn_mfma_f32_32x32x16_fp8_fp8(V[c].y, A1.y, acc[1][c], 0, 0, 0);
            }
            __builtin_amdgcn_s_setprio(0);
            if (k + 1 < NK) {
                A0 = nA0; A1 = nA1;
                #pragma unroll
                for (int c = 0; c < 4; ++c) V[c] = nV[c];
            }
        }

        // phase-partial epilogue: pure per-thread register reduction
        // (no max needed: |sims/tau| <= ~55 -> exp2 within fp32 range; exact)
        #pragma unroll
        for (int c = 0; c < 4; ++c) {
            s0 += expsum16(acc[0][c]);
            s1 += expsum16(acc[1][c]);
        }
        // bound intra-block wave drift so the 4 waves' identical B reads stay
        // L1-coincident (only 2 barriers total; nothing wanted is in flight)
        __syncthreads();
    }

    // merge lane>>5 halves (the only cross-lane step the swapped layout needs)
    s0 += __shfl_xor(s0, 32);
    s1 += __shfl_xor(s1, 32);
    constexpr float TAU_LN2 = 1.3862943611198906f;  // tau*ln2, tau=2
    float lse = TAU_LN2 * (log2f(s0) + log2f(s1));  // 2 rows' lse, this thread
    #pragma unroll
    for (int m = 1; m < 32; m <<= 1) lse += __shfl_xor(lse, m);
    if (lane == 0)
        atomicAdd(&out[bi * 32 + bj], lse * (1.0f / Na));  // 8 adds/output (rp)
}

extern "C" void kernel_launch(void* const* d_in, const int* in_sizes, int n_in,
                              void* d_out, int out_size, void* d_ws, size_t ws_size,
                              hipStream_t stream) {
    const float* audio  = (const float*)d_in[0];
    const float* visual = (const float*)d_in[1];
    float* out = (float*)d_out;

    unsigned char* a8 = (unsigned char*)d_ws;                        // 6.29 MB fp8 A
    unsigned char* b8 = a8 + (size_t)AGROUPS * GROUP_BYTES;          // +3.15 MB fp8 B

    convert_fp8_kernel<<<dim3(AGROUPS + BGROUPS), dim3(256), 0, stream>>>(
        audio, visual, a8, b8, out);
    // grid: 2048 blocks x 4 independent waves = 8192 waves
    //     = 32 bi x 32 bj x 8 row-pairs (64 rows x 256 cols each)
    gemm_lse_kernel<<<dim3(2048), dim3(256), 0, stream>>>(a8, b8, out);
}

// Round 2
// 150.481 us; speedup vs baseline: 1.1413x; 1.0185x over previous
//
#include <hip/hip_runtime.h>

// ---- problem constants (fixed by reference setup_inputs) ----
constexpr int B_  = 32;
constexpr int Na  = 512;
constexpr int Nv  = 256;
constexpr int D   = 384;

constexpr int BK  = 32;        // k-chunk per iteration
constexpr int NK  = D / BK;    // 12 k-iters

// fp8 operand regions: one 32-row group x 384 k = 12 chunks x 1 KB = 12 KB.
// Unit (group, kc) internal layout: byte = h2*512 + r*16 + j, holding
// value[row r][k = kc*32 + h2*16 + j]  (r = lane&31, k-half h2 = lane>>5).
// The (lane,byte)->k permutation is IDENTICAL for the MFMA A-slot and B-slot,
// so the contraction is exact for either operand role -> operands are swappable.
constexpr int AGROUPS = B_ * 16;   // 512 groups (bi*16+rg), rows linear
constexpr int BGROUPS = B_ * 8;    // 256 groups (bj*8+cg), rows linear
constexpr size_t GROUP_BYTES = 12 * 1024;

typedef long  long2v   __attribute__((ext_vector_type(2)));
typedef int   int4v    __attribute__((ext_vector_type(4)));
typedef float floatx16 __attribute__((ext_vector_type(16)));

// ---- K1: zero output + fp32 -> fp8(e4m3 OCP) conversion, BOTH sides coalesced ----
__global__ void convert_fp8_kernel(const float* __restrict__ a, const float* __restrict__ v,
                                   unsigned char* __restrict__ a8,
                                   unsigned char* __restrict__ b8,
                                   float* __restrict__ out) {
    int gid = blockIdx.x * blockDim.x + threadIdx.x;
    if (gid < B_ * B_) out[gid] = 0.0f;    // d_out is poisoned before every launch

    const float* src;
    unsigned char* dst;
    int blk = blockIdx.x;
    if (blk < AGROUPS) {                       // A rows are linear: group*32 + r
        src = a + (size_t)blk * 32 * D;
        dst = a8 + (size_t)blk * GROUP_BYTES;
    } else {
        int b2 = blk - AGROUPS;
        src = v + (size_t)b2 * 32 * D;
        dst = b8 + (size_t)b2 * GROUP_BYTES;
    }
    const int t = threadIdx.x;
    const int r = t >> 3, q = t & 7;

    #pragma unroll
    for (int p = 0; p < 3; ++p) {
        int k0 = p * 128 + q * 16;
        const float4* s4 = (const float4*)(src + (size_t)r * D + k0);
        float4 f0 = s4[0], f1 = s4[1], f2 = s4[2], f3 = s4[3];
        int w0 = 0, w1 = 0, w2 = 0, w3 = 0;
        w0 = __builtin_amdgcn_cvt_pk_fp8_f32(f0.x, f0.y, w0, false);
        w0 = __builtin_amdgcn_cvt_pk_fp8_f32(f0.z, f0.w, w0, true);
        w1 = __builtin_amdgcn_cvt_pk_fp8_f32(f1.x, f1.y, w1, false);
        w1 = __builtin_amdgcn_cvt_pk_fp8_f32(f1.z, f1.w, w1, true);
        w2 = __builtin_amdgcn_cvt_pk_fp8_f32(f2.x, f2.y, w2, false);
        w2 = __builtin_amdgcn_cvt_pk_fp8_f32(f2.z, f2.w, w2, true);
        w3 = __builtin_amdgcn_cvt_pk_fp8_f32(f3.x, f3.y, w3, false);
        w3 = __builtin_amdgcn_cvt_pk_fp8_f32(f3.z, f3.w, w3, true);
        int kc = k0 >> 5;
        int h2 = (k0 >> 4) & 1;
        int4v o = { w0, w1, w2, w3 };
        *(int4v*)(dst + (size_t)kc * 1024 + h2 * 512 + r * 16) = o;
    }
}

// sum of exp2(a[i] * 1/(tau*ln2)) over one accumulator, pairwise tree.
// RAW v_exp_f32 (__builtin_amdgcn_exp2f): |x| <= ~60, far inside the exact
// range [-126,128] of the HW instruction -> bit-identical to libm exp2f here,
// but 1 VALU op instead of OCML's ~6-10 op range-fixup expansion.
__device__ __forceinline__ float expsum16(floatx16 a) {
    constexpr float INV_TAU_LN2 = 0.7213475204444817f;  // 1/(tau*ln2), tau=2
    float e[16];
    #pragma unroll
    for (int i = 0; i < 16; ++i)
        e[i] = __builtin_amdgcn_exp2f(a[i] * INV_TAU_LN2);
    float t0 = (e[0] + e[1])  + (e[2] + e[3]);
    float t1 = (e[4] + e[5])  + (e[6] + e[7]);
    float t2 = (e[8] + e[9])  + (e[10] + e[11]);
    float t3 = (e[12] + e[13]) + (e[14] + e[15]);
    return (t0 + t1) + (t2 + t3);
}

// ---- K2: fused fp8 GEMM + logsumexp-pool, wave-independent, NO LDS, NO barriers ----
// B loads straight into VGPRs (lane-linear 16B fragments); L1/L2 provide the
// cross-wave reuse (full fp8 set = 9.4 MB, L2-resident).
// OPERAND SWAP: V in the MFMA A-slot, audio in the B-slot -> D col (lane&31) =
// audio row, regs = v indices -> Nv exp-sum is a per-thread register reduction
// + ONE shfl_xor(32).
// Wave tile: 64 audio rows x 128 v cols (acc[2][4] = 128 AGPRs), 2 phases for
// all 256 v. Register double-buffered prefetch, INCLUDING across the phase
// boundary (last k-iter of ph0 prefetches ph1's k=0 operands) so there is no
// cold-load bubble between phases. Zero barriers.
__global__ __launch_bounds__(256, 2) void gemm_lse_kernel(
        const unsigned char* __restrict__ a8,
        const unsigned char* __restrict__ b8,
        float* __restrict__ out)
{
    const int tid  = threadIdx.x;
    const int lane = tid & 63;
    const int wv   = tid >> 6;

    // XCD-chunked decode (block -> XCD = blockIdx%8): bi tied to XCD
    // => per-XCD L2 working set = A(4 bi)=786KB + B(all)=3.1MB ~= 3.9MB <= 4MB.
    int b = blockIdx.x;
    const int xcd   = b & 7;      b >>= 3;
    const int bi_lo = b & 3;      b >>= 2;
    const int pr    = b & 1;      b >>= 1;
    const int bj    = b;                      // 0..31
    const int bi    = xcd * 4 + bi_lo;        // 0..31
    const int rp    = pr * 4 + wv;            // 0..7 -> rows 64*rp .. +63

    const size_t laneoff = (size_t)lane * 16;
    const unsigned char* pa0 = a8 + (size_t)(bi * 16 + rp * 2) * GROUP_BYTES + laneoff;
    const unsigned char* pa1 = pa0 + GROUP_BYTES;
    const unsigned char* pb0 = b8 + (size_t)(bj * 8) * GROUP_BYTES + laneoff;

    float s0 = 0.0f, s1 = 0.0f;   // per-thread exp2-sums for audio rows
                                  // (rp*2)*32+(lane&31) and (rp*2+1)*32+(lane&31)

    // initial operand load (ph0, k0)
    long2v A0 = *(const long2v*)pa0;
    long2v A1 = *(const long2v*)pa1;
    long2v V[4];
    #pragma unroll
    for (int c = 0; c < 4; ++c)
        V[c] = *(const long2v*)(pb0 + (size_t)c * GROUP_BYTES);

    #pragma unroll
    for (int ph = 0; ph < 2; ++ph) {
        const unsigned char* pb = pb0 + (size_t)ph * 4 * GROUP_BYTES;

        floatx16 acc[2][4];
        #pragma unroll
        for (int r = 0; r < 2; ++r)
            #pragma unroll
            for (int c = 0; c < 4; ++c)
                acc[r][c] = (floatx16)(0.0f);

        #pragma unroll
        for (int k = 0; k < NK; ++k) {
            // prefetch next operands first (next k, or next phase's k=0);
            // one 16-MFMA cluster (~550 pipe-cy) covers L1/L2 latency
            long2v nA0, nA1, nV[4];
            const bool pre_k = (k + 1 < NK);
            const bool pre_p = (k + 1 == NK) && (ph == 0);
            if (pre_k) {
                const size_t o = (size_t)(k + 1) * 1024;
                nA0 = *(const long2v*)(pa0 + o);
                nA1 = *(const long2v*)(pa1 + o);
                #pragma unroll
                for (int c = 0; c < 4; ++c)
                    nV[c] = *(const long2v*)(pb + (size_t)c * GROUP_BYTES + o);
            } else if (pre_p) {
                nA0 = *(const long2v*)pa0;           // A restarts at k=0
                nA1 = *(const long2v*)pa1;
                #pragma unroll
                for (int c = 0; c < 4; ++c)          // ph1's 4 B-units
                    nV[c] = *(const long2v*)(pb0 + (size_t)(4 + c) * GROUP_BYTES);
            }
            // 16 MFMAs = 8 independent 2-chains (swapped operands: V in A-slot)
            __builtin_amdgcn_s_setprio(1);
            #pragma unroll
            for (int c = 0; c < 4; ++c) {
                acc[0][c] = __builtin_amdgcn_mfma_f32_32x32x16_fp8_fp8(V[c].x, A0.x, acc[0][c], 0, 0, 0);
                acc[1][c] = __builtin_amdgcn_mfma_f32_32x32x16_fp8_fp8(V[c].x, A1.x, acc[1][c], 0, 0, 0);
            }
            #pragma unroll
            for (int c = 0; c < 4; ++c) {
                acc[0][c] = __builtin_amdgcn_mfma_f32_32x32x16_fp8_fp8(V[c].y, A0.y, acc[0][c], 0, 0, 0);
                acc[1][c] = __builtin_amdgcn_mfma_f32_32x32x16_fp8_fp8(V[c].y, A1.y, acc[1][c], 0, 0, 0);
            }
            __builtin_amdgcn_s_setprio(0);
            if (pre_k | pre_p) {
                A0 = nA0; A1 = nA1;
                #pragma unroll
                for (int c = 0; c < 4; ++c) V[c] = nV[c];
            }
        }

        // phase-partial epilogue: pure per-thread register reduction
        // (no max needed: |sims/tau| <= ~55 -> exp2 within fp32 range; exact)
        #pragma unroll
        for (int c = 0; c < 4; ++c) {
            s0 += expsum16(acc[0][c]);
            s1 += expsum16(acc[1][c]);
        }
    }

    // merge lane>>5 halves (the only cross-lane step the swapped layout needs)
    s0 += __shfl_xor(s0, 32);
    s1 += __shfl_xor(s1, 32);
    constexpr float TAU_LN2 = 1.3862943611198906f;  // tau*ln2, tau=2
    float lse = TAU_LN2 * (__builtin_amdgcn_logf(s0) + __builtin_amdgcn_logf(s1));
    #pragma unroll
    for (int m = 1; m < 32; m <<= 1) lse += __shfl_xor(lse, m);
    if (lane == 0)
        atomicAdd(&out[bi * 32 + bj], lse * (1.0f / Na));  // 8 adds/output (rp)
}

extern "C" void kernel_launch(void* const* d_in, const int* in_sizes, int n_in,
                              void* d_out, int out_size, void* d_ws, size_t ws_size,
                              hipStream_t stream) {
    const float* audio  = (const float*)d_in[0];
    const float* visual = (const float*)d_in[1];
    float* out = (float*)d_out;

    unsigned char* a8 = (unsigned char*)d_ws;                        // 6.29 MB fp8 A
    unsigned char* b8 = a8 + (size_t)AGROUPS * GROUP_BYTES;          // +3.15 MB fp8 B

    convert_fp8_kernel<<<dim3(AGROUPS + BGROUPS), dim3(256), 0, stream>>>(
        audio, visual, a8, b8, out);
    // grid: 2048 blocks x 4 independent waves = 8192 waves
    //     = 32 bi x 32 bj x 8 row-pairs (64 rows x 256 cols each)
    gemm_lse_kernel<<<dim3(2048), dim3(256), 0, stream>>>(a8, b8, out);
}